// Round 9
// baseline (106.745 us; speedup 1.0000x reference)
//
#include <hip/hip_runtime.h>

// EdgewiseEnergySum:
//   out[n] = 0.125 * sum_{e : center(e)==n} edge_eng[e] * scales[sp[center(e)], sp[neighbor(e)]]
//
// R1: 6.4M device atomics -> 344 us (memory-side atomic throttle).
// R2: bucket counting-sort -> 162 us.  R3: species 2-bit LDS table -> 120 us.
// R6: single-pass reg-resident K1 -> 119 us.  R7: 512-thr blocks -> 101 us.
// R8: 4B records + 1563 blocks -> 105 us (K1 55 us; VALU 10%, HBM 15%,
//     FETCH 38MB < input 77MB -> L3-resident; everything latency-bound).
// R9: kill phase A (histogram) + phase B (global range alloc) via FIXED
//     per-(chunk,bucket) regions CAP=88 (mean 41.8 + 7sigma); K1 persistent
//     with atomic chunk queue (table loaded once per block, zero tail
//     imbalance); K1 writes 98 counts/chunk; K2 walks segments wave-parallel.

#define BUCKET_SHIFT 10
#define BUCKET_NODES 1024
#define MAX_NB       128
#define CAP          88               // per-(chunk,bucket) capacity: 41.8 + ~7 sigma
#define K1_THREADS   512
#define K1_BLOCKS    1024             // 4 blocks/CU * 256 CU, persistent
#define CHUNK        4096             // 512 threads * 8 edges
#define NSTRIPE      8                // K2 blocks per bucket
#define MAX_SP_WORDS 6272             // 2-bit species, 16/word (25 KB)

// ---------------- K0: pack species 2-bit + zero chunk queue ---------------
__global__ void k0_pack(const int* __restrict__ species,
                        unsigned int* __restrict__ packed,
                        int* __restrict__ qhead,
                        int n_nodes, int n_words)
{
    const int w = blockIdx.x * blockDim.x + threadIdx.x;
    if (w == 0) *qhead = 0;
    if (w >= n_words) return;
    const int base = w * 16;
    unsigned int v = 0;
    if (base + 16 <= n_nodes) {
#pragma unroll
        for (int q = 0; q < 4; ++q) {
            const int4 s4 = *(const int4*)(species + base + 4 * q);
            v |= (unsigned int)(s4.x & 3) << (8 * q + 0);
            v |= (unsigned int)(s4.y & 3) << (8 * q + 2);
            v |= (unsigned int)(s4.z & 3) << (8 * q + 4);
            v |= (unsigned int)(s4.w & 3) << (8 * q + 6);
        }
    } else {
        const int m = n_nodes - base;
        for (int j = 0; j < m; ++j)
            v |= (unsigned int)(species[base + j] & 3) << (2 * j);
    }
    packed[w] = v;
}

// ---------------- K1: persistent scatter, fixed regions, no alloc phase ---
__global__ void __launch_bounds__(K1_THREADS)
k1_scatter(const float* __restrict__ edge_eng,
           const int*   __restrict__ edge_center,
           const int*   __restrict__ edge_neighbor,
           const unsigned int* __restrict__ sp_packed,
           const float* __restrict__ scales,
           unsigned int* __restrict__ recs,   // [n_chunks][NB][CAP]
           int*          __restrict__ cnts,   // [n_chunks][NB]
           int*          __restrict__ qhead,  // chunk queue (zeroed by k0)
           int n_edges, int n_chunks, int nb, int n_sp_words)
{
    __shared__ unsigned int s_sp[MAX_SP_WORDS];  // 25 KB, loaded ONCE per block
    __shared__ float s_scale[16];
    __shared__ int cursor[MAX_NB];
    __shared__ int s_cid;

    const int tid = threadIdx.x;
    if (tid < 16) s_scale[tid] = scales[tid] * 0.125f;   // fold 1/sqrt(64)
    for (int i = tid; i < n_sp_words; i += K1_THREADS) s_sp[i] = sp_packed[i];
    for (int b = tid; b < nb; b += K1_THREADS) cursor[b] = 0;
    // (no barrier needed here; B1 below orders before first use)

    for (;;) {
        if (tid == 0) s_cid = atomicAdd(qhead, 1);
        __syncthreads();                         // B1: s_cid + cursors ready
        const int cid = s_cid;
        if (cid >= n_chunks) break;

        const int lo = cid * CHUNK;

        // ---- load this thread's 8 edges into registers -------------------
        int4   c4[2];
        int4   n4[2];
        float4 e4[2];
        const bool full = ((n_edges & 3) == 0) && (lo + CHUNK <= n_edges);
        if (full) {
#pragma unroll
            for (int k = 0; k < 2; ++k) {
                const int idx = lo + 4 * tid + (4 * K1_THREADS) * k;
                c4[k] = *(const int4*)  (edge_center   + idx);
                n4[k] = *(const int4*)  (edge_neighbor + idx);
                e4[k] = *(const float4*)(edge_eng      + idx);
            }
        } else {
#pragma unroll
            for (int k = 0; k < 2; ++k) {
                const int idx = lo + 4 * tid + (4 * K1_THREADS) * k;
                int*   cp = (int*)  &c4[k];
                int*   np = (int*)  &n4[k];
                float* ep = (float*)&e4[k];
#pragma unroll
                for (int j = 0; j < 4; ++j) {
                    const int i = idx + j;
                    if (i < n_edges) { cp[j] = edge_center[i]; np[j] = edge_neighbor[i]; ep[j] = edge_eng[i]; }
                    else             { cp[j] = -1; np[j] = 0; ep[j] = 0.0f; }
                }
            }
        }

        // ---- scatter 4B records into fixed (cid,bucket) regions ----------
        const size_t reg_base = (size_t)cid * nb * CAP;
#define SP(n) ((s_sp[(unsigned)(n) >> 4] >> (((n) & 15) << 1)) & 3)
#pragma unroll
        for (int k = 0; k < 2; ++k) {
            const int*   cp = (const int*)  &c4[k];
            const int*   np = (const int*)  &n4[k];
            const float* ep = (const float*)&e4[k];
#pragma unroll
            for (int j = 0; j < 4; ++j) {
                const int c = cp[j];
                if (c < 0) continue;
                const int   b = c >> BUCKET_SHIFT;
                const float v = ep[j] * s_scale[(SP(c) << 2) | SP(np[j])];
                const unsigned int rec = (__float_as_uint(v) & 0xFFFFFC00u)
                                       | ((unsigned int)c & (BUCKET_NODES - 1));
                const int r = atomicAdd(&cursor[b], 1);       // LDS atomic
                if (r < CAP)                                  // ~7-sigma guard
                    recs[reg_base + (size_t)b * CAP + r] = rec;
            }
        }
#undef SP
        __syncthreads();                         // B2: all scatters done

        // ---- write counts, rezero cursors (B1 of next iter orders) -------
        for (int b = tid; b < nb; b += K1_THREADS) {
            cnts[cid * nb + b] = cursor[b];
            cursor[b] = 0;
        }
    }
}

// ---------------- K2: per-(bucket,stripe) segment accumulation ------------
__global__ void k2_accumulate(const unsigned int* __restrict__ recs,
                              const int*  __restrict__ cnts,
                              float*      __restrict__ partials, // [NB][NSTRIPE][1024]
                              int n_chunks, int nb)
{
    __shared__ float acc[BUCKET_NODES];
    __shared__ int s_cnt[256];                   // counts for this stripe's segments
    const int b    = blockIdx.x / NSTRIPE;
    const int s    = blockIdx.x % NSTRIPE;
    const int tid  = threadIdx.x;
    const int lane = tid & 63;
    const int wav  = tid >> 6;                   // 4 waves

    const int nseg = (n_chunks - s + NSTRIPE - 1) / NSTRIPE;  // cid = s + 8*t

    for (int i = tid; i < BUCKET_NODES; i += blockDim.x) acc[i] = 0.0f;
    for (int t = tid; t < nseg; t += blockDim.x) {
        const int cid = s + NSTRIPE * t;
        int c = cnts[cid * nb + b];
        s_cnt[t] = (c < CAP) ? c : CAP;
    }
    __syncthreads();

    for (int t = wav; t < nseg; t += 4) {        // one segment per wave
        const int cid = s + NSTRIPE * t;
        const int cnt = s_cnt[t];
        const unsigned int* p = recs + ((size_t)cid * nb + b) * CAP;
        for (int i = lane; i < cnt; i += 64) {   // usually 1 iteration (cnt~42)
            const unsigned int r = p[i];
            atomicAdd(&acc[r & (BUCKET_NODES - 1)],
                      __uint_as_float(r & 0xFFFFFC00u));
        }
    }
    __syncthreads();

    float* dst = partials + (size_t)blockIdx.x * BUCKET_NODES;
    for (int i = tid; i < BUCKET_NODES; i += blockDim.x) dst[i] = acc[i];
}

// ---------------- K3: reduce NSTRIPE partials, plain store ----------------
__global__ void k3_reduce(const float* __restrict__ partials,
                          float*       __restrict__ out, int n_nodes)
{
    const int n = blockIdx.x * blockDim.x + threadIdx.x;
    if (n >= n_nodes) return;
    const int b     = n >> BUCKET_SHIFT;
    const int local = n & (BUCKET_NODES - 1);
    const float* p  = partials + (size_t)b * NSTRIPE * BUCKET_NODES + local;
    float sum = 0.0f;
#pragma unroll
    for (int i = 0; i < NSTRIPE; ++i) sum += p[i * BUCKET_NODES];
    out[n] = sum;
}

// ---------------- Fallback: atomic kernel (if ws too small) ---------------
__global__ void fallback_atomic_kernel(const float* __restrict__ edge_eng,
                                       const int*   __restrict__ edge_center,
                                       const int*   __restrict__ edge_neighbor,
                                       const int*   __restrict__ species,
                                       const float* __restrict__ scales,
                                       float*       __restrict__ out, int n_edges)
{
    __shared__ float s_scale[16];
    if (threadIdx.x < 16) s_scale[threadIdx.x] = scales[threadIdx.x] * 0.125f;
    __syncthreads();
    const int stride = gridDim.x * blockDim.x;
    for (int i = blockIdx.x * blockDim.x + threadIdx.x; i < n_edges; i += stride) {
        const int c  = edge_center[i];
        const int cs = species[c];
        const int ns = species[edge_neighbor[i]];
        atomicAdd(&out[c], edge_eng[i] * s_scale[(cs << 2) | ns]);
    }
}

extern "C" void kernel_launch(void* const* d_in, const int* in_sizes, int n_in,
                              void* d_out, int out_size, void* d_ws, size_t ws_size,
                              hipStream_t stream) {
    const float* edge_eng   = (const float*)d_in[0];
    const int*   edge_index = (const int*)  d_in[1];
    const int*   species    = (const int*)  d_in[2];
    const float* scales     = (const float*)d_in[3];
    float*       out        = (float*)      d_out;

    const int n_edges = in_sizes[1] / 2;
    const int n_nodes = in_sizes[2];
    const int* edge_center   = edge_index;
    const int* edge_neighbor = edge_index + n_edges;

    const int nb       = (n_nodes + BUCKET_NODES - 1) >> BUCKET_SHIFT;
    const int n_words  = (n_nodes + 15) / 16;
    const int n_chunks = (n_edges + CHUNK - 1) / CHUNK;

    // ws layout: [qhead: 4096 pad][packed][recs][cnts][partials]
    const size_t off_qhead    = 0;
    const size_t off_packed   = 4096;
    const size_t off_recs     = (off_packed + (size_t)n_words * 4 + 255) & ~(size_t)255;
    const size_t off_cnts     = off_recs + (size_t)n_chunks * nb * CAP * 4;
    const size_t off_partials = (off_cnts + (size_t)n_chunks * nb * 4 + 255) & ~(size_t)255;
    const size_t needed       = off_partials + (size_t)nb * NSTRIPE * BUCKET_NODES * 4;

    if (nb > MAX_NB || n_words > MAX_SP_WORDS ||
        (n_chunks + NSTRIPE - 1) / NSTRIPE > 256 ||      // K2 s_cnt sizing
        ws_size < needed) {
        hipMemsetAsync(d_out, 0, (size_t)out_size * sizeof(float), stream);
        int grid = (n_edges + 255) / 256;
        if (grid > 2048) grid = 2048;
        fallback_atomic_kernel<<<grid, 256, 0, stream>>>(
            edge_eng, edge_center, edge_neighbor, species, scales, out, n_edges);
        return;
    }

    int*          qhead    = (int*)         ((char*)d_ws + off_qhead);
    unsigned int* packed   = (unsigned int*)((char*)d_ws + off_packed);
    unsigned int* recs     = (unsigned int*)((char*)d_ws + off_recs);
    int*          cnts     = (int*)         ((char*)d_ws + off_cnts);
    float*        partials = (float*)       ((char*)d_ws + off_partials);

    k0_pack<<<(n_words + 255) / 256, 256, 0, stream>>>(
        species, packed, qhead, n_nodes, n_words);

    k1_scatter<<<K1_BLOCKS, K1_THREADS, 0, stream>>>(
        edge_eng, edge_center, edge_neighbor, packed, scales,
        recs, cnts, qhead, n_edges, n_chunks, nb, n_words);

    k2_accumulate<<<nb * NSTRIPE, 256, 0, stream>>>(recs, cnts, partials, n_chunks, nb);

    k3_reduce<<<(n_nodes + 255) / 256, 256, 0, stream>>>(partials, out, n_nodes);
}

// Round 10
// 88.837 us; speedup vs baseline: 1.2016x; 1.2016x over previous
//
#include <hip/hip_runtime.h>

// EdgewiseEnergySum:
//   out[n] = 0.125 * sum_{e : center(e)==n} edge_eng[e] * scales[sp[center(e)], sp[neighbor(e)]]
//
// R1: 6.4M global atomics -> 344 us.  R2: counting-sort -> 162 us.
// R3: species LDS table -> 120 us.  R7: 512-thr -> 101 us (K1 66).
// R8: 4B records -> 105 us (K1 55; best K1).  R9: persistent+fixed regions
//     -> 107 us (K1 65 at occ 74% -> occupancy NOT the limit; per-edge
//     serial pipe work is; scattered 4B stores ~1 TA-line/edge dominate).
// R10: LDS-staged records: scatter into per-bucket LDS lists (padded
//      stride 81 vs 80 to spread banks), then wave-coalesced copy-out to
//      fixed (chunk,bucket) regions. Scattered-store TA cost ~1 ->
//      ~0.06 lines/edge. Fixed regions: no global counter atomics;
//      overflow -> global spill list drained by K4 (correctness, ~never hit).

#define BUCKET_SHIFT 10
#define BUCKET_NODES 1024
#define STAGE_NB     104              // LDS sizing; actual nb = 98
#define CAP          80               // per-(chunk,bucket): mean 41.9 + 6 sigma
#define STR          81               // padded LDS stride (81%32=17, odd -> spread)
#define K1_THREADS   512
#define CHUNK        4096             // 512 threads * 8 edges
#define NSTRIPE      8                // K2 blocks per bucket
#define MAX_SP_WORDS 6272             // 2-bit species, 16/word (25 KB)
#define OVF_CAP      8192

// ---------------- K0: pack species 2-bit + zero overflow counter ----------
__global__ void k0_pack(const int* __restrict__ species,
                        unsigned int* __restrict__ packed,
                        int* __restrict__ ovf_cnt,
                        int n_nodes, int n_words)
{
    const int w = blockIdx.x * blockDim.x + threadIdx.x;
    if (w == 0) *ovf_cnt = 0;
    if (w >= n_words) return;
    const int base = w * 16;
    unsigned int v = 0;
    if (base + 16 <= n_nodes) {
#pragma unroll
        for (int q = 0; q < 4; ++q) {
            const int4 s4 = *(const int4*)(species + base + 4 * q);
            v |= (unsigned int)(s4.x & 3) << (8 * q + 0);
            v |= (unsigned int)(s4.y & 3) << (8 * q + 2);
            v |= (unsigned int)(s4.z & 3) << (8 * q + 4);
            v |= (unsigned int)(s4.w & 3) << (8 * q + 6);
        }
    } else {
        const int m = n_nodes - base;
        for (int j = 0; j < m; ++j)
            v |= (unsigned int)(species[base + j] & 3) << (2 * j);
    }
    packed[w] = v;
}

// ---------------- K1: LDS-staged scatter, coalesced copy-out --------------
__global__ void __launch_bounds__(K1_THREADS)
k1_scatter(const float* __restrict__ edge_eng,
           const int*   __restrict__ edge_center,
           const int*   __restrict__ edge_neighbor,
           const unsigned int* __restrict__ sp_packed,
           const float* __restrict__ scales,
           unsigned int* __restrict__ recs,     // [n_chunks][nb][CAP]
           int*          __restrict__ cnts,     // [n_chunks][nb]
           int2*         __restrict__ ovf,
           int*          __restrict__ ovf_cnt,
           int n_edges, int nb, int n_sp_words)
{
    __shared__ unsigned int s_sp[MAX_SP_WORDS];    // 25.1 KB
    __shared__ unsigned int stage[STAGE_NB * STR]; // 33.7 KB
    __shared__ float s_scale[16];
    __shared__ int cursor[STAGE_NB];

    const int tid = threadIdx.x;
    if (tid < 16) s_scale[tid] = scales[tid] * 0.125f;   // fold 1/sqrt(64)
    for (int i = tid; i < n_sp_words; i += K1_THREADS) s_sp[i] = sp_packed[i];
    for (int b = tid; b < nb; b += K1_THREADS) cursor[b] = 0;
    __syncthreads();

    const int cid = blockIdx.x;
    const int lo  = cid * CHUNK;

    // ---- Load this thread's 8 edges ONCE into registers ------------------
    int4   c4[2];
    int4   n4[2];
    float4 e4[2];
    const bool full = ((n_edges & 3) == 0) && (lo + CHUNK <= n_edges);
    if (full) {
#pragma unroll
        for (int k = 0; k < 2; ++k) {
            const int idx = lo + 4 * tid + (4 * K1_THREADS) * k;
            c4[k] = *(const int4*)  (edge_center   + idx);
            n4[k] = *(const int4*)  (edge_neighbor + idx);
            e4[k] = *(const float4*)(edge_eng      + idx);
        }
    } else {
#pragma unroll
        for (int k = 0; k < 2; ++k) {
            const int idx = lo + 4 * tid + (4 * K1_THREADS) * k;
            int*   cp = (int*)  &c4[k];
            int*   np = (int*)  &n4[k];
            float* ep = (float*)&e4[k];
#pragma unroll
            for (int j = 0; j < 4; ++j) {
                const int i = idx + j;
                if (i < n_edges) { cp[j] = edge_center[i]; np[j] = edge_neighbor[i]; ep[j] = edge_eng[i]; }
                else             { cp[j] = -1; np[j] = 0; ep[j] = 0.0f; }
            }
        }
    }

    // ---- Scatter 4B records into per-bucket LDS lists --------------------
#define SP(n) ((s_sp[(unsigned)(n) >> 4] >> (((n) & 15) << 1)) & 3)
#pragma unroll
    for (int k = 0; k < 2; ++k) {
        const int*   cp = (const int*)  &c4[k];
        const int*   np = (const int*)  &n4[k];
        const float* ep = (const float*)&e4[k];
#pragma unroll
        for (int j = 0; j < 4; ++j) {
            const int c = cp[j];
            if (c < 0) continue;
            const int   b = c >> BUCKET_SHIFT;
            const float v = ep[j] * s_scale[(SP(c) << 2) | SP(np[j])];
            const unsigned int rec = (__float_as_uint(v) & 0xFFFFFC00u)
                                   | ((unsigned int)c & (BUCKET_NODES - 1));
            const int r = atomicAdd(&cursor[b], 1);          // LDS atomic
            if (r < CAP) {
                stage[b * STR + r] = rec;                    // LDS write
            } else {                                         // ~never: spill
                const int oi = atomicAdd(ovf_cnt, 1);
                if (oi < OVF_CAP) ovf[oi] = make_int2(c, __float_as_int(v));
            }
        }
    }
#undef SP
    __syncthreads();

    // ---- Coalesced copy-out: one wave per bucket list --------------------
    const int wav  = tid >> 6;
    const int lane = tid & 63;
    for (int b = wav; b < nb; b += (K1_THREADS / 64)) {
        const int cnt = min(cursor[b], CAP);
        unsigned int* dst = recs + ((size_t)cid * nb + b) * CAP;
        for (int i = lane; i < cnt; i += 64) dst[i] = stage[b * STR + i];
        if (lane == 0) cnts[cid * nb + b] = cnt;
    }
}

// ---------------- K2: per-(bucket,stripe) segment accumulation ------------
__global__ void k2_accumulate(const unsigned int* __restrict__ recs,
                              const int*  __restrict__ cnts,
                              float*      __restrict__ partials, // [NB][NSTRIPE][1024]
                              int n_chunks, int nb)
{
    __shared__ float acc[BUCKET_NODES];
    __shared__ int s_cnt[256];
    const int b    = blockIdx.x / NSTRIPE;
    const int s    = blockIdx.x % NSTRIPE;
    const int tid  = threadIdx.x;
    const int lane = tid & 63;
    const int wav  = tid >> 6;                   // 4 waves

    const int nseg = (n_chunks - s + NSTRIPE - 1) / NSTRIPE;  // cid = s + 8*t

    for (int i = tid; i < BUCKET_NODES; i += blockDim.x) acc[i] = 0.0f;
    for (int t = tid; t < nseg; t += blockDim.x) {
        const int cid = s + NSTRIPE * t;
        s_cnt[t] = cnts[cid * nb + b];           // already clamped to CAP by K1
    }
    __syncthreads();

    for (int t = wav; t < nseg; t += 4) {        // one segment per wave
        const int cid = s + NSTRIPE * t;
        const int cnt = s_cnt[t];
        const unsigned int* p = recs + ((size_t)cid * nb + b) * CAP;
        for (int i = lane; i < cnt; i += 64) {   // cnt<=80 -> <=2 iters
            const unsigned int r = p[i];
            atomicAdd(&acc[r & (BUCKET_NODES - 1)],
                      __uint_as_float(r & 0xFFFFFC00u));
        }
    }
    __syncthreads();

    float* dst = partials + (size_t)blockIdx.x * BUCKET_NODES;
    for (int i = tid; i < BUCKET_NODES; i += blockDim.x) dst[i] = acc[i];
}

// ---------------- K3: reduce NSTRIPE partials, plain store ----------------
__global__ void k3_reduce(const float* __restrict__ partials,
                          float*       __restrict__ out, int n_nodes)
{
    const int n = blockIdx.x * blockDim.x + threadIdx.x;
    if (n >= n_nodes) return;
    const int b     = n >> BUCKET_SHIFT;
    const int local = n & (BUCKET_NODES - 1);
    const float* p  = partials + (size_t)b * NSTRIPE * BUCKET_NODES + local;
    float sum = 0.0f;
#pragma unroll
    for (int i = 0; i < NSTRIPE; ++i) sum += p[i * BUCKET_NODES];
    out[n] = sum;
}

// ---------------- K4: drain overflow spill (normally empty) ---------------
__global__ void k4_overflow(const int2* __restrict__ ovf,
                            const int*  __restrict__ ovf_cnt,
                            float*      __restrict__ out)
{
    const int n = min(*ovf_cnt, OVF_CAP);
    for (int i = threadIdx.x; i < n; i += blockDim.x)
        atomicAdd(&out[ovf[i].x], __int_as_float(ovf[i].y));
}

// ---------------- Fallback: atomic kernel (if ws too small) ---------------
__global__ void fallback_atomic_kernel(const float* __restrict__ edge_eng,
                                       const int*   __restrict__ edge_center,
                                       const int*   __restrict__ edge_neighbor,
                                       const int*   __restrict__ species,
                                       const float* __restrict__ scales,
                                       float*       __restrict__ out, int n_edges)
{
    __shared__ float s_scale[16];
    if (threadIdx.x < 16) s_scale[threadIdx.x] = scales[threadIdx.x] * 0.125f;
    __syncthreads();
    const int stride = gridDim.x * blockDim.x;
    for (int i = blockIdx.x * blockDim.x + threadIdx.x; i < n_edges; i += stride) {
        const int c  = edge_center[i];
        const int cs = species[c];
        const int ns = species[edge_neighbor[i]];
        atomicAdd(&out[c], edge_eng[i] * s_scale[(cs << 2) | ns]);
    }
}

extern "C" void kernel_launch(void* const* d_in, const int* in_sizes, int n_in,
                              void* d_out, int out_size, void* d_ws, size_t ws_size,
                              hipStream_t stream) {
    const float* edge_eng   = (const float*)d_in[0];
    const int*   edge_index = (const int*)  d_in[1];
    const int*   species    = (const int*)  d_in[2];
    const float* scales     = (const float*)d_in[3];
    float*       out        = (float*)      d_out;

    const int n_edges = in_sizes[1] / 2;
    const int n_nodes = in_sizes[2];
    const int* edge_center   = edge_index;
    const int* edge_neighbor = edge_index + n_edges;

    const int nb       = (n_nodes + BUCKET_NODES - 1) >> BUCKET_SHIFT;
    const int n_words  = (n_nodes + 15) / 16;
    const int n_chunks = (n_edges + CHUNK - 1) / CHUNK;

    // ws layout: [ovf_cnt: 4096 pad][packed][recs][cnts][partials][ovf]
    const size_t off_ovfcnt   = 0;
    const size_t off_packed   = 4096;
    const size_t off_recs     = (off_packed + (size_t)n_words * 4 + 255) & ~(size_t)255;
    const size_t off_cnts     = off_recs + (size_t)n_chunks * nb * CAP * 4;
    const size_t off_partials = (off_cnts + (size_t)n_chunks * nb * 4 + 255) & ~(size_t)255;
    const size_t off_ovf      = off_partials + (size_t)nb * NSTRIPE * BUCKET_NODES * 4;
    const size_t needed       = off_ovf + (size_t)OVF_CAP * sizeof(int2);

    if (nb > STAGE_NB || n_words > MAX_SP_WORDS ||
        (n_chunks + NSTRIPE - 1) / NSTRIPE > 256 ||      // K2 s_cnt sizing
        ws_size < needed) {
        hipMemsetAsync(d_out, 0, (size_t)out_size * sizeof(float), stream);
        int grid = (n_edges + 255) / 256;
        if (grid > 2048) grid = 2048;
        fallback_atomic_kernel<<<grid, 256, 0, stream>>>(
            edge_eng, edge_center, edge_neighbor, species, scales, out, n_edges);
        return;
    }

    int*          ovf_cnt  = (int*)         ((char*)d_ws + off_ovfcnt);
    unsigned int* packed   = (unsigned int*)((char*)d_ws + off_packed);
    unsigned int* recs     = (unsigned int*)((char*)d_ws + off_recs);
    int*          cnts     = (int*)         ((char*)d_ws + off_cnts);
    float*        partials = (float*)       ((char*)d_ws + off_partials);
    int2*         ovf      = (int2*)        ((char*)d_ws + off_ovf);

    k0_pack<<<(n_words + 255) / 256, 256, 0, stream>>>(
        species, packed, ovf_cnt, n_nodes, n_words);

    k1_scatter<<<n_chunks, K1_THREADS, 0, stream>>>(
        edge_eng, edge_center, edge_neighbor, packed, scales,
        recs, cnts, ovf, ovf_cnt, n_edges, nb, n_words);

    k2_accumulate<<<nb * NSTRIPE, 256, 0, stream>>>(recs, cnts, partials, n_chunks, nb);

    k3_reduce<<<(n_nodes + 255) / 256, 256, 0, stream>>>(partials, out, n_nodes);

    k4_overflow<<<1, 256, 0, stream>>>(ovf, ovf_cnt, out);
}